// Round 2
// baseline (834.047 us; speedup 1.0000x reference)
//
#include <hip/hip_runtime.h>
#include <hip/hip_bf16.h>

// Problem constants (CrossNetMixFuxiCTR): B=16384, D=2048, L=3, E=8, R=64
#define BDIM 16384
#define DDIM 2048
#define LNUM 3
#define ENUM 8
#define NP 24            // L*E (l,e) pairs

// GEMM tile
#define BM 256           // rows per block (4 waves x 64 rows)
#define BK 32            // f16 k-elements per iter (64 B/row)

typedef _Float16 f16x8 __attribute__((ext_vector_type(8)));
typedef _Float16 f16x4 __attribute__((ext_vector_type(4)));
typedef float f32x4 __attribute__((ext_vector_type(4)));

// ------- convert U,V -> Wh f16, layout [p=24][128 rows: 64 U then 64 V][D] -------
__global__ void cvt_w_kernel(const float* __restrict__ U, const float* __restrict__ V,
                             _Float16* __restrict__ Wh) {
    size_t f = (size_t)blockIdx.x * blockDim.x + threadIdx.x;   // float4 index
    size_t elem = f * 4;
    int d   = (int)(elem & (DDIM - 1));
    int row = (int)((elem >> 11) & 127);   // /2048 % 128
    int p   = (int)(elem >> 18);           // /(2048*128)
    const float* src = (row < 64)
        ? (U + ((size_t)(p * 64 + row) * DDIM + d))
        : (V + ((size_t)(p * 64 + (row - 64)) * DDIM + d));
    float4 v = *(const float4*)src;
    f16x4 h = { (_Float16)v.x, (_Float16)v.y, (_Float16)v.z, (_Float16)v.w };
    ((f16x4*)Wh)[f] = h;
}

// ---- fused: gate logits G[j][b] = X0[b].Wg[j] (fp32)  +  X0 -> X0h f16 conversion ----
// one wave handles 4 rows; block = 4 waves = 16 rows; float4-vectorized loads
__global__ void gate_kernel(const float* __restrict__ X0, const float* __restrict__ Wg,
                            float* __restrict__ G, _Float16* __restrict__ X0h) {
    const int wave = threadIdx.x >> 6;
    const int lane = threadIdx.x & 63;
    const int b0 = (blockIdx.x * 4 + wave) * 4;
    float acc[4][NP];
#pragma unroll
    for (int i = 0; i < 4; ++i)
#pragma unroll
        for (int j = 0; j < NP; ++j) acc[i][j] = 0.f;
    const float* xp = X0 + (size_t)b0 * DDIM;
#pragma unroll 1
    for (int it = 0; it < DDIM / 256; ++it) {      // 8 iters, float4 col index
        int c = it * 64 + lane;
        float4 x[4];
#pragma unroll
        for (int i = 0; i < 4; ++i) x[i] = ((const float4*)(xp + (size_t)i * DDIM))[c];
#pragma unroll
        for (int i = 0; i < 4; ++i) {
            f16x4 h = { (_Float16)x[i].x, (_Float16)x[i].y, (_Float16)x[i].z, (_Float16)x[i].w };
            ((f16x4*)(X0h + (size_t)(b0 + i) * DDIM))[c] = h;
        }
#pragma unroll
        for (int j = 0; j < NP; ++j) {
            float4 w = ((const float4*)(Wg + (size_t)j * DDIM))[c];
#pragma unroll
            for (int i = 0; i < 4; ++i)
                acc[i][j] += x[i].x * w.x + x[i].y * w.y + x[i].z * w.z + x[i].w * w.w;
        }
    }
#pragma unroll
    for (int i = 0; i < 4; ++i)
#pragma unroll
        for (int j = 0; j < NP; ++j) {
            float v = acc[i][j];
            v += __shfl_xor(v, 1);
            v += __shfl_xor(v, 2);
            v += __shfl_xor(v, 4);
            v += __shfl_xor(v, 8);
            v += __shfl_xor(v, 16);
            v += __shfl_xor(v, 32);
            if (lane == 0) G[(size_t)j * BDIM + (b0 + i)] = v;
        }
}

// ---------------- MFMA GEMM + in-wave bilinear reduction ----------------
// Block: 256 thr (4 waves). Tile: 256 rows x 128 cols (one (l,e): cols 0-63 = PU, 64-127 = PV).
// Wave w computes rows [w*64, w*64+64) x all 128 cols -> 4x8 tiles of 16x16x32 f16 MFMA,
// 32 MFMA per 12 ds_read_b128 per k-iter (0.375 reads/MFMA; was 0.625).
// LDS XOR swizzle: position chunk c of row r holds global k-chunk c ^ sigma(r),
// sigma(r) = (r>>1)&3 -> read groups are 2-way per bank (free), kills the 4-way conflicts.
// T[p][m] = sum_r PU[m][r]*PV[m][r] via in-lane acc[mi][ni]*acc[mi][ni+4] + butterfly.
__global__ __launch_bounds__(256, 2) void gemm_t_kernel(
    const _Float16* __restrict__ Ah,   // [BDIM][DDIM] f16
    const _Float16* __restrict__ Bh,   // [NP][128][DDIM] f16
    float* __restrict__ T)             // [NP][BDIM]
{
    const int p    = blockIdx.y;
    const int m0   = blockIdx.x * BM;
    const int tid  = (int)threadIdx.x;
    const int wave = tid >> 6;
    const int lane = tid & 63;
    const int mlane = lane & 15;
    const int quad  = lane >> 4;

    __shared__ _Float16 As[BM * BK];    // 16 KB
    __shared__ _Float16 Bs[128 * BK];   // 8 KB

    const _Float16* Bp = Bh + (size_t)p * 128 * DDIM;

    f32x4 acc[4][8];
#pragma unroll
    for (int i = 0; i < 4; ++i)
#pragma unroll
        for (int j = 0; j < 8; ++j) acc[i][j] = (f32x4){0.f, 0.f, 0.f, 0.f};

    const int srow = lane >> 2;                              // 0..15 within 16-row chunk
    const int scol = ((lane & 3) ^ ((lane >> 3) & 3)) * 8;   // swizzled global f16 col
    const int sw   = (mlane >> 1) & 3;                       // sigma(row) for reads

    for (int k0 = 0; k0 < DDIM; k0 += BK) {
        __syncthreads();   // previous iter's LDS reads done before overwrite
#pragma unroll
        for (int q = 0; q < 4; ++q) {                        // A: 64 own rows
            int r16 = wave * 64 + q * 16;
            const _Float16* ga = Ah + (size_t)(m0 + r16 + srow) * DDIM + k0 + scol;
            __builtin_amdgcn_global_load_lds(
                (const __attribute__((address_space(1))) void*)ga,
                (__attribute__((address_space(3))) void*)&As[r16 * BK], 16, 0, 0);
        }
#pragma unroll
        for (int q = 0; q < 2; ++q) {                        // B: 32 rows per wave
            int r16 = wave * 32 + q * 16;
            const _Float16* gb = Bp + (size_t)(r16 + srow) * DDIM + k0 + scol;
            __builtin_amdgcn_global_load_lds(
                (const __attribute__((address_space(1))) void*)gb,
                (__attribute__((address_space(3))) void*)&Bs[r16 * BK], 16, 0, 0);
        }
        __syncthreads();   // drains vmcnt -> staged data visible

        f16x8 aF[4], bF[8];
#pragma unroll
        for (int mi = 0; mi < 4; ++mi)
            aF[mi] = *(const f16x8*)&As[(wave * 64 + mi * 16 + mlane) * BK + ((quad ^ sw) * 8)];
#pragma unroll
        for (int ni = 0; ni < 8; ++ni)
            bF[ni] = *(const f16x8*)&Bs[(ni * 16 + mlane) * BK + ((quad ^ sw) * 8)];
#pragma unroll
        for (int mi = 0; mi < 4; ++mi)
#pragma unroll
            for (int ni = 0; ni < 8; ++ni)
                acc[mi][ni] = __builtin_amdgcn_mfma_f32_16x16x32_f16(
                    aF[mi], bF[ni], acc[mi][ni], 0, 0, 0);
    }

    // C/D layout: col = lane&15, row = quad*4 + reg. PU col r at ni=r/16, PV at ni+4 (same lane).
#pragma unroll
    for (int mi = 0; mi < 4; ++mi) {
#pragma unroll
        for (int j = 0; j < 4; ++j) {
            float tp = 0.f;
#pragma unroll
            for (int ni = 0; ni < 4; ++ni)
                tp += acc[mi][ni][j] * acc[mi][ni + 4][j];
            tp += __shfl_xor(tp, 1);
            tp += __shfl_xor(tp, 2);
            tp += __shfl_xor(tp, 4);
            tp += __shfl_xor(tp, 8);
            if (mlane == 0) {
                int m = wave * 64 + mi * 16 + quad * 4 + j;
                T[(size_t)p * BDIM + (m0 + m)] = tp;
            }
        }
    }
}

// ---------------- per-row scalar recurrence + scaled write-out (reads X0h f16) ----------------
__global__ void epilogue_kernel(const _Float16* __restrict__ X0h,
                                const float* __restrict__ T,
                                const float* __restrict__ G,
                                const float* __restrict__ bg,
                                float* __restrict__ out) {
    __shared__ float s_sh[16];
    const int b0 = blockIdx.x * 16;
    const int tid = (int)threadIdx.x;
    if (tid < 16) {
        int b = b0 + tid;
        float s = 1.f;
#pragma unroll
        for (int l = 0; l < LNUM; ++l) {
            float logit[ENUM];
            float mx = -1e30f;
#pragma unroll
            for (int e = 0; e < ENUM; ++e) {
                int j = l * ENUM + e;
                float g = s * G[(size_t)j * BDIM + b] + bg[j];
                logit[e] = g;
                mx = fmaxf(mx, g);
            }
            float den = 0.f, num = 0.f;
            float s2 = s * s;
#pragma unroll
            for (int e = 0; e < ENUM; ++e) {
                int j = l * ENUM + e;
                float w = __expf(logit[e] - mx);
                den += w;
                num += w * (s2 * T[(size_t)j * BDIM + b]);
            }
            s += num / den;
        }
        s_sh[tid] = s;
    }
    __syncthreads();
    const int nf4 = DDIM / 4;   // 512 float4 per row
    for (int idx = tid; idx < 16 * nf4; idx += 256) {
        int r = idx >> 9;
        int c = idx & (nf4 - 1);
        float s = s_sh[r];
        f16x4 h = ((const f16x4*)(X0h + (size_t)(b0 + r) * DDIM))[c];
        float4 x = { s * (float)h[0], s * (float)h[1], s * (float)h[2], s * (float)h[3] };
        ((float4*)(out + (size_t)(b0 + r) * DDIM))[c] = x;
    }
}

extern "C" void kernel_launch(void* const* d_in, const int* in_sizes, int n_in,
                              void* d_out, int out_size, void* d_ws, size_t ws_size,
                              hipStream_t stream) {
    const float* X0 = (const float*)d_in[0];
    const float* U  = (const float*)d_in[1];
    const float* V  = (const float*)d_in[2];
    const float* Wg = (const float*)d_in[3];
    const float* bg = (const float*)d_in[4];
    float* out = (float*)d_out;

    // workspace layout (~82.8 MB)
    char* ws = (char*)d_ws;
    _Float16* X0h = (_Float16*)ws;                                   // 16384*2048*2 = 67108864
    _Float16* Wh  = (_Float16*)(ws + 67108864ull);                   // 24*128*2048*2 = 12582912
    float* T      = (float*)(ws + 67108864ull + 12582912ull);        // 24*16384*4 = 1572864
    float* G      = (float*)(ws + 67108864ull + 12582912ull + 1572864ull);

    cvt_w_kernel<<<dim3((NP * 128 * DDIM / 4) / 256), dim3(256), 0, stream>>>(U, V, Wh);
    gate_kernel<<<dim3(BDIM / 16), dim3(256), 0, stream>>>(X0, Wg, G, X0h);
    gemm_t_kernel<<<dim3(BDIM / BM, NP), dim3(256), 0, stream>>>(X0h, Wh, T);
    epilogue_kernel<<<dim3(BDIM / 16), dim3(256), 0, stream>>>(X0h, T, G, bg, out);
}

// Round 3
// 542.023 us; speedup vs baseline: 1.5388x; 1.5388x over previous
//
#include <hip/hip_runtime.h>
#include <hip/hip_bf16.h>

// Problem constants (CrossNetMixFuxiCTR): B=16384, D=2048, L=3, E=8, R=64
#define BDIM 16384
#define DDIM 2048
#define LNUM 3
#define ENUM 8
#define NP 24            // L*E (l,e) pairs

// GEMM tile
#define BM 256           // rows per block (4 waves x 64 rows)
#define BK 32            // f16 k-elements per iter (64 B/row)

typedef _Float16 f16x8 __attribute__((ext_vector_type(8)));
typedef _Float16 f16x4 __attribute__((ext_vector_type(4)));
typedef float f32x4 __attribute__((ext_vector_type(4)));

// ------- convert U,V -> Wh f16, layout [p=24][128 rows: 64 U then 64 V][D] -------
__global__ void cvt_w_kernel(const float* __restrict__ U, const float* __restrict__ V,
                             _Float16* __restrict__ Wh) {
    size_t f = (size_t)blockIdx.x * blockDim.x + threadIdx.x;   // float4 index
    size_t elem = f * 4;
    int d   = (int)(elem & (DDIM - 1));
    int row = (int)((elem >> 11) & 127);   // /2048 % 128
    int p   = (int)(elem >> 18);           // /(2048*128)
    const float* src = (row < 64)
        ? (U + ((size_t)(p * 64 + row) * DDIM + d))
        : (V + ((size_t)(p * 64 + (row - 64)) * DDIM + d));
    float4 v = *(const float4*)src;
    f16x4 h = { (_Float16)v.x, (_Float16)v.y, (_Float16)v.z, (_Float16)v.w };
    ((f16x4*)Wh)[f] = h;
}

// ---- fused: gate logits G[j][b] = X0[b].Wg[j] (fp32)  +  X0 -> X0h f16 conversion ----
// 64 rows/block (256 blocks = 1/CU). Each thread: 2 rows (rq, rq+32), 1/8 of k (q = tid&7).
// Wg staged in LDS in 256-float k-chunks (24 KB); w-reads are 8-addr x 8-lane broadcast
// (conflict-free). acc[2][24] = 48 VGPRs -> no spill (R2's VGPR=64 + 835 MB scratch bug).
__global__ __launch_bounds__(256, 4) void gate_kernel(
    const float* __restrict__ X0, const float* __restrict__ Wg,
    float* __restrict__ G, _Float16* __restrict__ X0h) {
    __shared__ float Wgs[NP * 256];   // 24 KB
    const int tid = (int)threadIdx.x;
    const int rq  = tid >> 3;          // 0..31
    const int q   = tid & 7;           // k-slice
    const int r0  = blockIdx.x * 64 + rq;
    const int r1  = r0 + 32;

    float acc[2][NP];
#pragma unroll
    for (int r = 0; r < 2; ++r)
#pragma unroll
        for (int j = 0; j < NP; ++j) acc[r][j] = 0.f;

    const float4* x0p = (const float4*)(X0 + (size_t)r0 * DDIM);
    const float4* x1p = (const float4*)(X0 + (size_t)r1 * DDIM);
    f16x4* h0p = (f16x4*)(X0h + (size_t)r0 * DDIM);
    f16x4* h1p = (f16x4*)(X0h + (size_t)r1 * DDIM);

    for (int k0 = 0; k0 < DDIM; k0 += 256) {
        __syncthreads();
        // stage Wg[0:24][k0:k0+256) -> LDS: 1536 float4 by 256 threads
#pragma unroll
        for (int t = tid; t < NP * 64; t += 256)
            ((float4*)Wgs)[t] =
                ((const float4*)Wg)[(size_t)(t >> 6) * (DDIM / 4) + (k0 >> 2) + (t & 63)];
        __syncthreads();
#pragma unroll 2
        for (int i = 0; i < 8; ++i) {
            int f4 = i * 8 + q;                 // float4 index within chunk [0,64)
            int gc = (k0 >> 2) + f4;            // global float4 column
            float4 x0 = x0p[gc];
            float4 x1 = x1p[gc];
            f16x4 h0 = { (_Float16)x0.x, (_Float16)x0.y, (_Float16)x0.z, (_Float16)x0.w };
            f16x4 h1 = { (_Float16)x1.x, (_Float16)x1.y, (_Float16)x1.z, (_Float16)x1.w };
            h0p[gc] = h0;
            h1p[gc] = h1;
#pragma unroll
            for (int j = 0; j < NP; ++j) {
                float4 w = ((const float4*)(Wgs + j * 256))[f4];
                acc[0][j] += x0.x * w.x + x0.y * w.y + x0.z * w.z + x0.w * w.w;
                acc[1][j] += x1.x * w.x + x1.y * w.y + x1.z * w.z + x1.w * w.w;
            }
        }
    }
    // reduce over the 8 k-slices (lanes differing in bits 0..2)
#pragma unroll
    for (int r = 0; r < 2; ++r)
#pragma unroll
        for (int j = 0; j < NP; ++j) {
            float v = acc[r][j];
            v += __shfl_xor(v, 1);
            v += __shfl_xor(v, 2);
            v += __shfl_xor(v, 4);
            if (q == 0) G[(size_t)j * BDIM + (r == 0 ? r0 : r1)] = v;
        }
}

// ---------------- MFMA GEMM + in-wave bilinear reduction ----------------
// Block: 256 thr (4 waves). Tile: 256 rows x 128 cols (one (l,e): cols 0-63 = PU, 64-127 = PV).
// Wave w computes rows [w*64, w*64+64) x all 128 cols -> 4x8 tiles of 16x16x32 f16 MFMA,
// 32 MFMA per 12 ds_read_b128 per k-iter (0.375 reads/MFMA).
// LDS XOR swizzle: position chunk c of row r holds global k-chunk c ^ sigma(r),
// sigma(r) = (r>>1)&3 -> read groups are 2-way per bank (free), kills the 4-way conflicts.
// T[p][m] = sum_r PU[m][r]*PV[m][r] via in-lane acc[mi][ni]*acc[mi][ni+4] + butterfly.
__global__ __launch_bounds__(256, 2) void gemm_t_kernel(
    const _Float16* __restrict__ Ah,   // [BDIM][DDIM] f16
    const _Float16* __restrict__ Bh,   // [NP][128][DDIM] f16
    float* __restrict__ T)             // [NP][BDIM]
{
    const int p    = blockIdx.y;
    const int m0   = blockIdx.x * BM;
    const int tid  = (int)threadIdx.x;
    const int wave = tid >> 6;
    const int lane = tid & 63;
    const int mlane = lane & 15;
    const int quad  = lane >> 4;

    __shared__ _Float16 As[BM * BK];    // 16 KB
    __shared__ _Float16 Bs[128 * BK];   // 8 KB

    const _Float16* Bp = Bh + (size_t)p * 128 * DDIM;

    f32x4 acc[4][8];
#pragma unroll
    for (int i = 0; i < 4; ++i)
#pragma unroll
        for (int j = 0; j < 8; ++j) acc[i][j] = (f32x4){0.f, 0.f, 0.f, 0.f};

    const int srow = lane >> 2;                              // 0..15 within 16-row chunk
    const int scol = ((lane & 3) ^ ((lane >> 3) & 3)) * 8;   // swizzled global f16 col
    const int sw   = (mlane >> 1) & 3;                       // sigma(row) for reads

    for (int k0 = 0; k0 < DDIM; k0 += BK) {
        __syncthreads();   // previous iter's LDS reads done before overwrite
#pragma unroll
        for (int q = 0; q < 4; ++q) {                        // A: 64 own rows
            int r16 = wave * 64 + q * 16;
            const _Float16* ga = Ah + (size_t)(m0 + r16 + srow) * DDIM + k0 + scol;
            __builtin_amdgcn_global_load_lds(
                (const __attribute__((address_space(1))) void*)ga,
                (__attribute__((address_space(3))) void*)&As[r16 * BK], 16, 0, 0);
        }
#pragma unroll
        for (int q = 0; q < 2; ++q) {                        // B: 32 rows per wave
            int r16 = wave * 32 + q * 16;
            const _Float16* gb = Bp + (size_t)(r16 + srow) * DDIM + k0 + scol;
            __builtin_amdgcn_global_load_lds(
                (const __attribute__((address_space(1))) void*)gb,
                (__attribute__((address_space(3))) void*)&Bs[r16 * BK], 16, 0, 0);
        }
        __syncthreads();   // drains vmcnt -> staged data visible

        f16x8 aF[4], bF[8];
#pragma unroll
        for (int mi = 0; mi < 4; ++mi)
            aF[mi] = *(const f16x8*)&As[(wave * 64 + mi * 16 + mlane) * BK + ((quad ^ sw) * 8)];
#pragma unroll
        for (int ni = 0; ni < 8; ++ni)
            bF[ni] = *(const f16x8*)&Bs[(ni * 16 + mlane) * BK + ((quad ^ sw) * 8)];
#pragma unroll
        for (int mi = 0; mi < 4; ++mi)
#pragma unroll
            for (int ni = 0; ni < 8; ++ni)
                acc[mi][ni] = __builtin_amdgcn_mfma_f32_16x16x32_f16(
                    aF[mi], bF[ni], acc[mi][ni], 0, 0, 0);
    }

    // C/D layout: col = lane&15, row = quad*4 + reg. PU col r at ni=r/16, PV at ni+4 (same lane).
#pragma unroll
    for (int mi = 0; mi < 4; ++mi) {
#pragma unroll
        for (int j = 0; j < 4; ++j) {
            float tp = 0.f;
#pragma unroll
            for (int ni = 0; ni < 4; ++ni)
                tp += acc[mi][ni][j] * acc[mi][ni + 4][j];
            tp += __shfl_xor(tp, 1);
            tp += __shfl_xor(tp, 2);
            tp += __shfl_xor(tp, 4);
            tp += __shfl_xor(tp, 8);
            if (mlane == 0) {
                int m = wave * 64 + mi * 16 + quad * 4 + j;
                T[(size_t)p * BDIM + (m0 + m)] = tp;
            }
        }
    }
}

// ---------------- per-row scalar recurrence + scaled write-out (reads X0h f16) ----------------
__global__ void epilogue_kernel(const _Float16* __restrict__ X0h,
                                const float* __restrict__ T,
                                const float* __restrict__ G,
                                const float* __restrict__ bg,
                                float* __restrict__ out) {
    __shared__ float s_sh[16];
    const int b0 = blockIdx.x * 16;
    const int tid = (int)threadIdx.x;
    if (tid < 16) {
        int b = b0 + tid;
        float s = 1.f;
#pragma unroll
        for (int l = 0; l < LNUM; ++l) {
            float logit[ENUM];
            float mx = -1e30f;
#pragma unroll
            for (int e = 0; e < ENUM; ++e) {
                int j = l * ENUM + e;
                float g = s * G[(size_t)j * BDIM + b] + bg[j];
                logit[e] = g;
                mx = fmaxf(mx, g);
            }
            float den = 0.f, num = 0.f;
            float s2 = s * s;
#pragma unroll
            for (int e = 0; e < ENUM; ++e) {
                int j = l * ENUM + e;
                float w = __expf(logit[e] - mx);
                den += w;
                num += w * (s2 * T[(size_t)j * BDIM + b]);
            }
            s += num / den;
        }
        s_sh[tid] = s;
    }
    __syncthreads();
    const int nf4 = DDIM / 4;   // 512 float4 per row
    for (int idx = tid; idx < 16 * nf4; idx += 256) {
        int r = idx >> 9;
        int c = idx & (nf4 - 1);
        float s = s_sh[r];
        f16x4 h = ((const f16x4*)(X0h + (size_t)(b0 + r) * DDIM))[c];
        float4 x = { s * (float)h[0], s * (float)h[1], s * (float)h[2], s * (float)h[3] };
        ((float4*)(out + (size_t)(b0 + r) * DDIM))[c] = x;
    }
}

extern "C" void kernel_launch(void* const* d_in, const int* in_sizes, int n_in,
                              void* d_out, int out_size, void* d_ws, size_t ws_size,
                              hipStream_t stream) {
    const float* X0 = (const float*)d_in[0];
    const float* U  = (const float*)d_in[1];
    const float* V  = (const float*)d_in[2];
    const float* Wg = (const float*)d_in[3];
    const float* bg = (const float*)d_in[4];
    float* out = (float*)d_out;

    // workspace layout (~82.8 MB)
    char* ws = (char*)d_ws;
    _Float16* X0h = (_Float16*)ws;                                   // 16384*2048*2 = 67108864
    _Float16* Wh  = (_Float16*)(ws + 67108864ull);                   // 24*128*2048*2 = 12582912
    float* T      = (float*)(ws + 67108864ull + 12582912ull);        // 24*16384*4 = 1572864
    float* G      = (float*)(ws + 67108864ull + 12582912ull + 1572864ull);

    cvt_w_kernel<<<dim3((NP * 128 * DDIM / 4) / 256), dim3(256), 0, stream>>>(U, V, Wh);
    gate_kernel<<<dim3(BDIM / 64), dim3(256), 0, stream>>>(X0, Wg, G, X0h);
    gemm_t_kernel<<<dim3(BDIM / BM, NP), dim3(256), 0, stream>>>(X0h, Wh, T);
    epilogue_kernel<<<dim3(BDIM / 16), dim3(256), 0, stream>>>(X0h, T, G, bg, out);
}